// Round 10
// baseline (105.879 us; speedup 1.0000x reference)
//
#include <hip/hip_runtime.h>
#include <hip/hip_bf16.h>

// Chamfer distance, B=4, N=M=8192, D=3, fp32.
// R9: mega-fused GEMM-style kernel. R8 diagnosis: 2048 short-lived blocks ->
// prologue/epilogue ~= main loop; pack kernel + 4MB L2 round-trip wasted.
// Now: 1024 blocks (4/CU), each 128 rows x 4096 cols via 4 staged LDS
// col-tiles (K-loop). Split-bf16 packing (verified absmax 0.0 in R7/R8)
// happens IN-KERNEL: A-frags in registers from raw inputs, B-payloads during
// LDS staging. Reduce = 1 block, no atomics, writes out[0] directly.
// Graph: 2 kernels, no memsets. ws: 512 KB partials only.
//   payload k0..15 (AxB): -2h.h | -2l.h | -2h.l | qn.1 | 1.tn | 0
//   A: [ax,ay,az, cx,cy,cz, ax,ay,az, n1,n2,n3, 1,1,1, 0]
//   B: [hx,hy,hz, hx,hy,hz, lx,ly,lz, 1,1,1, n1,n2,n3, 0]
// C/D layout 32x32 (m74/m101): col=lane&31, row=(reg&3)+8*(reg>>2)+4*(lane>>5)

typedef __attribute__((ext_vector_type(8)))  short short8;
typedef __attribute__((ext_vector_type(16))) float f32x16;

#define BATCH 4
#define NPTS 8192
#define TOTALQ (BATCH * NPTS)   // 32768
#define BLK 256
#define BROWS 128               // rows per block (4 waves x one 32-row tile)
#define NCH (TOTALQ / BROWS)    // 256 row chunks per dir
#define MSPLIT 2                // col slices per batch
#define MRANGE (NPTS / MSPLIT)  // 4096 cols per block
#define MC 1024                 // cols per LDS stage
#define NSTAGE (MRANGE / MC)    // 4 stages
#define MT_PER (MC / 32)        // 32 m-tiles per stage

__device__ __forceinline__ unsigned short f2bf(float f) {  // RTN-even
    unsigned int u = __float_as_uint(f);
    u += 0x7FFFu + ((u >> 16) & 1u);
    return (unsigned short)(u >> 16);
}
__device__ __forceinline__ float bf2f(unsigned short h) {
    return __uint_as_float(((unsigned int)h) << 16);
}
__device__ __forceinline__ unsigned int pk2(unsigned short a, unsigned short b) {
    return (unsigned int)a | ((unsigned int)b << 16);
}

// split x,y,z + norm into the 15-slot payload pieces
struct Payload {
    unsigned short hx, hy, hz, lx, ly, lz, n1, n2, n3;
};
__device__ __forceinline__ Payload split_point(float x, float y, float z) {
    Payload P;
    P.hx = f2bf(x);  P.hy = f2bf(y);  P.hz = f2bf(z);
    P.lx = f2bf(x - bf2f(P.hx));
    P.ly = f2bf(y - bf2f(P.hy));
    P.lz = f2bf(z - bf2f(P.hz));
    float nrm = fmaf(z, z, fmaf(y, y, x * x));
    P.n1 = f2bf(nrm);
    float r1 = nrm - bf2f(P.n1);
    P.n2 = f2bf(r1);
    P.n3 = f2bf(r1 - bf2f(P.n2));
    return P;
}

__global__ __launch_bounds__(BLK) void chamfer_mega_kernel(
        const float* __restrict__ pred, const float* __restrict__ target,
        float* __restrict__ part)
{
    const int dir = blockIdx.z;
    const float* __restrict__ Q  = dir ? target : pred;   // rows (A)
    const float* __restrict__ Tg = dir ? pred : target;   // cols (B)

    const int nch = blockIdx.x;            // 0..255
    const int b   = nch >> 6;              // batch (64 chunks per batch)
    const int ms  = blockIdx.y;            // 0..1 col slice
    const int w    = threadIdx.x >> 6;
    const int lane = threadIdx.x & 63;
    const int c = lane & 31;               // row (A) / col (B) within tile
    const int g = lane >> 5;               // k-half
    const unsigned short ONE = 0x3F80;

    __shared__ uint4 ldsb[2][MC];          // 32 KB (two k-halves)

    // ---- A fragment: in-register pack of row (rowstart + c), k-half g ----
    const int rowstart = nch * BROWS + w * 32;   // global point id
    short8 afrag;
    {
        int r = rowstart + c;
        float x = Q[3 * r], y = Q[3 * r + 1], z = Q[3 * r + 2];
        Payload P = split_point(x, y, z);
        // -2*h, -2*l exact (power-of-2 scale)
        unsigned short ax = f2bf(-2.f * bf2f(P.hx)),
                       ay = f2bf(-2.f * bf2f(P.hy)),
                       az = f2bf(-2.f * bf2f(P.hz));
        unsigned short cx = f2bf(-2.f * bf2f(P.lx)),
                       cy = f2bf(-2.f * bf2f(P.ly)),
                       cz = f2bf(-2.f * bf2f(P.lz));
        uint4 h0 = { pk2(ax, ay), pk2(az, cx), pk2(cy, cz), pk2(ax, ay) };
        uint4 h1 = { pk2(az, P.n1), pk2(P.n2, P.n3), pk2(ONE, ONE), pk2(ONE, 0) };
        uint4 sel = g ? h1 : h0;
        afrag = *(short8*)&sel;
    }

    f32x16 acc;
    #pragma unroll
    for (int r = 0; r < 16; ++r) acc[r] = 3.4e38f;
    const f32x16 zacc = (f32x16)(0.f);

    const size_t colbase = (size_t)b * NPTS + (size_t)ms * MRANGE;

    for (int st = 0; st < NSTAGE; ++st) {
        // ---- stage MC target points: raw read -> payload -> LDS ----
        __syncthreads();                   // protect prior stage's reads
        #pragma unroll
        for (int j = 0; j < MC / BLK; ++j) {
            int p = j * BLK + threadIdx.x;
            size_t gp = colbase + st * MC + p;
            float x = Tg[3 * gp], y = Tg[3 * gp + 1], z = Tg[3 * gp + 2];
            Payload P = split_point(x, y, z);
            ldsb[0][p] = (uint4){ pk2(P.hx, P.hy), pk2(P.hz, P.hx),
                                  pk2(P.hy, P.hz), pk2(P.lx, P.ly) };
            ldsb[1][p] = (uint4){ pk2(P.lz, ONE), pk2(ONE, ONE),
                                  pk2(P.n1, P.n2), pk2(P.n3, 0) };
        }
        __syncthreads();

        // ---- main loop: 2 ds_read_b128 + 2 MFMA + 16 min3 per 2 m-tiles ----
        const ushort* ldsu = (const ushort*)&ldsb[g][0];   // this lane's k-half
        #pragma unroll 2
        for (int mt = 0; mt < MT_PER; mt += 2) {
            short8 bf0 = *(const short8*)(ldsu + (mt * 32 + c) * 8);
            short8 bf1 = *(const short8*)(ldsu + ((mt + 1) * 32 + c) * 8);
            f32x16 d0 = __builtin_amdgcn_mfma_f32_32x32x16_bf16(
                            afrag, bf0, zacc, 0, 0, 0);
            f32x16 d1 = __builtin_amdgcn_mfma_f32_32x32x16_bf16(
                            afrag, bf1, zacc, 0, 0, 0);
            #pragma unroll
            for (int r = 0; r < 16; ++r)
                acc[r] = fminf(fminf(acc[r], d0[r]), d1[r]);   // v_min3
        }
    }

    // ---- epilogue: fold 32 cols (xor within 32-lane half), store rows ----
    #pragma unroll
    for (int m = 1; m < 32; m <<= 1) {
        #pragma unroll
        for (int r = 0; r < 16; ++r)
            acc[r] = fminf(acc[r], __shfl_xor(acc[r], m, 64));
    }
    float* rp = part + (size_t)(dir * MSPLIT + ms) * TOTALQ + rowstart;
    #pragma unroll
    for (int r = 0; r < 16; ++r) {
        int row = (r & 3) + 8 * (r >> 2) + 4 * g;   // C/D row map (m74/m101)
        if (c == r) rp[row] = acc[r];
    }
}

__global__ __launch_bounds__(1024) void chamfer_reduce_kernel(
        const float* __restrict__ part, float* __restrict__ out)
{
    float acc = 0.0f;
    #pragma unroll
    for (int dir = 0; dir < 2; ++dir) {
        const float* p0 = part + (size_t)(dir * MSPLIT) * TOTALQ;
        const float* p1 = p0 + TOTALQ;
        for (int i = threadIdx.x; i < TOTALQ; i += 1024)
            acc += fminf(p0[i], p1[i]);
    }
    acc *= (1.0f / (float)TOTALQ);
    #pragma unroll
    for (int off = 32; off > 0; off >>= 1)
        acc += __shfl_down(acc, off, 64);
    __shared__ float wsum[16];
    int lane = threadIdx.x & 63, wid = threadIdx.x >> 6;
    if (lane == 0) wsum[wid] = acc;
    __syncthreads();
    if (threadIdx.x == 0) {
        float s = 0.0f;
        #pragma unroll
        for (int wv = 0; wv < 16; ++wv) s += wsum[wv];
        out[0] = s;
    }
}

extern "C" void kernel_launch(void* const* d_in, const int* in_sizes, int n_in,
                              void* d_out, int out_size, void* d_ws, size_t ws_size,
                              hipStream_t stream) {
    const float* pred   = (const float*)d_in[0];
    const float* target = (const float*)d_in[1];
    float*       out    = (float*)d_out;
    float*       part   = (float*)d_ws;   // 2 dirs x 2 slices x 32768 = 512 KB

    dim3 grid(NCH, MSPLIT, 2);            // 256 x 2 x 2 = 1024 blocks
    hipLaunchKernelGGL(chamfer_mega_kernel, grid, dim3(BLK), 0, stream,
                       pred, target, part);

    hipLaunchKernelGGL(chamfer_reduce_kernel, dim3(1), dim3(1024), 0, stream,
                       (const float*)part, out);
}

// Round 11
// 89.552 us; speedup vs baseline: 1.1823x; 1.1823x over previous
//
#include <hip/hip_runtime.h>
#include <hip/hip_bf16.h>

// Chamfer distance, B=4, N=M=8192, D=3, fp32.
// R10: kill the AGPR<->VGPR shuttle. R8/R10 counters showed ~28 us of VALU
// busy vs a ~4 us min-fold model across two different structures -> theory:
// compiler puts MFMA D/C in AGPRs (VGPR_Count=52!) and emits v_accvgpr_read
// per element before every fminf. Fix: inline-asm MFMA with "=&v" outputs
// (gfx950 unified file: v[] legal for D/C) + explicit s_nop hazard padding,
// so v_min3_f32 reads MFMA results directly from VGPRs.
// Also WNT=4 A-tiles/wave: 8 MFMAs per 2 ds_read_b128 (LDS pipe ~2.6 us).
// Payload (verified absmax 0.0 in R7-R10), k0..15 A x B:
//   -2h.h | -2l.h | -2h.l | qn.1 | 1.tn | 0
// C/D layout 32x32 (m74/m101): col=lane&31, row=(reg&3)+8*(reg>>2)+4*(lane>>5)

typedef __attribute__((ext_vector_type(8)))  short short8;
typedef __attribute__((ext_vector_type(16))) float f32x16;

#define BATCH 4
#define NPTS 8192
#define TOTALQ (BATCH * NPTS)   // 32768
#define BLK 256
#define WNT 4                   // 32-row tiles per wave -> 128 rows/wave
#define BROWS 512               // rows per block (4 waves)
#define MSPLIT 8                // col slices per batch
#define MC (NPTS / MSPLIT)      // 1024 cols per block, single LDS stage
#define MT_PER (MC / 32)        // 32 m-tiles

__device__ __forceinline__ unsigned short f2bf(float f) {  // RTN-even
    unsigned int u = __float_as_uint(f);
    u += 0x7FFFu + ((u >> 16) & 1u);
    return (unsigned short)(u >> 16);
}
__device__ __forceinline__ float bf2f(unsigned short h) {
    return __uint_as_float(((unsigned int)h) << 16);
}
__device__ __forceinline__ unsigned int pk2(unsigned short a, unsigned short b) {
    return (unsigned int)a | ((unsigned int)b << 16);
}

struct Payload {
    unsigned short hx, hy, hz, lx, ly, lz, n1, n2, n3;
};
__device__ __forceinline__ Payload split_point(float x, float y, float z) {
    Payload P;
    P.hx = f2bf(x);  P.hy = f2bf(y);  P.hz = f2bf(z);
    P.lx = f2bf(x - bf2f(P.hx));
    P.ly = f2bf(y - bf2f(P.hy));
    P.lz = f2bf(z - bf2f(P.hz));
    float nrm = fmaf(z, z, fmaf(y, y, x * x));
    P.n1 = f2bf(nrm);
    float r1 = nrm - bf2f(P.n1);
    P.n2 = f2bf(r1);
    P.n3 = f2bf(r1 - bf2f(P.n2));
    return P;
}

__global__ __launch_bounds__(BLK) void chamfer_mega_kernel(
        const float* __restrict__ pred, const float* __restrict__ target,
        float* __restrict__ part, float* __restrict__ out)
{
    const int dir = blockIdx.z;
    const float* __restrict__ Q  = dir ? target : pred;   // rows (A)
    const float* __restrict__ Tg = dir ? pred : target;   // cols (B)

    const int nch = blockIdx.x;            // 0..63 (512-row chunk)
    const int b   = nch >> 4;              // batch (16 chunks per batch)
    const int ms  = blockIdx.y;            // 0..7 col slice
    const int w    = threadIdx.x >> 6;
    const int lane = threadIdx.x & 63;
    const int c = lane & 31;               // row (A) / col (B) within tile
    const int g = lane >> 5;               // k-half
    const unsigned short ONE = 0x3F80;

    if (blockIdx.x == 0 && blockIdx.y == 0 && blockIdx.z == 0 &&
        threadIdx.x == 0) out[0] = 0.0f;   // consumed after kernel boundary

    __shared__ uint4 ldsb[2][MC];          // 32 KB (two k-halves)

    // ---- stage MC target points: raw read -> payload -> LDS ----
    #pragma unroll
    for (int j = 0; j < MC / BLK; ++j) {
        int p = j * BLK + threadIdx.x;
        size_t gp = (size_t)b * NPTS + (size_t)ms * MC + p;
        float x = Tg[3 * gp], y = Tg[3 * gp + 1], z = Tg[3 * gp + 2];
        Payload P = split_point(x, y, z);
        ldsb[0][p] = (uint4){ pk2(P.hx, P.hy), pk2(P.hz, P.hx),
                              pk2(P.hy, P.hz), pk2(P.lx, P.ly) };
        ldsb[1][p] = (uint4){ pk2(P.lz, ONE), pk2(ONE, ONE),
                              pk2(P.n1, P.n2), pk2(P.n3, 0) };
    }

    // ---- A fragments: in-register pack, row = rowstart + nt*32 + c ----
    const int rowstart = nch * BROWS + w * (WNT * 32);
    short8 afrag[WNT];
    #pragma unroll
    for (int nt = 0; nt < WNT; ++nt) {
        int r = rowstart + nt * 32 + c;
        float x = Q[3 * r], y = Q[3 * r + 1], z = Q[3 * r + 2];
        Payload P = split_point(x, y, z);
        unsigned short ax = f2bf(-2.f * bf2f(P.hx)),
                       ay = f2bf(-2.f * bf2f(P.hy)),
                       az = f2bf(-2.f * bf2f(P.hz));
        unsigned short cx = f2bf(-2.f * bf2f(P.lx)),
                       cy = f2bf(-2.f * bf2f(P.ly)),
                       cz = f2bf(-2.f * bf2f(P.lz));
        uint4 h0 = { pk2(ax, ay), pk2(az, cx), pk2(cy, cz), pk2(ax, ay) };
        uint4 h1 = { pk2(az, P.n1), pk2(P.n2, P.n3), pk2(ONE, ONE), pk2(ONE, 0) };
        uint4 sel = g ? h1 : h0;
        afrag[nt] = *(short8*)&sel;
    }

    f32x16 acc[WNT];
    #pragma unroll
    for (int nt = 0; nt < WNT; ++nt)
        #pragma unroll
        for (int r = 0; r < 16; ++r) acc[nt][r] = 3.4e38f;

    f32x16 vzero;
    #pragma unroll
    for (int r = 0; r < 16; ++r) vzero[r] = 0.0f;

    __syncthreads();

    const ushort* ldsu = (const ushort*)&ldsb[g][0];   // this lane's k-half

    // ---- main loop: 2 ds_read_b128 + 8 MFMA (VGPR-dst asm) + 64 min3 ----
    for (int mt = 0; mt < MT_PER; mt += 2) {
        short8 bf0 = *(const short8*)(ldsu + (mt * 32 + c) * 8);
        short8 bf1 = *(const short8*)(ldsu + ((mt + 1) * 32 + c) * 8);
        #pragma unroll
        for (int nt = 0; nt < WNT; ++nt) {
            f32x16 d0, d1;
            // VGPR-destination MFMA; s_nop pads the D-write -> VALU-read
            // hazard (8-pass MFMA) since the hazard recognizer can't see
            // inside the asm.
            asm("v_mfma_f32_32x32x16_bf16 %0, %2, %3, %5\n\t"
                "v_mfma_f32_32x32x16_bf16 %1, %2, %4, %5\n\t"
                "s_nop 7\n\t"
                "s_nop 7"
                : "=&v"(d0), "=&v"(d1)
                : "v"(afrag[nt]), "v"(bf0), "v"(bf1), "v"(vzero));
            #pragma unroll
            for (int r = 0; r < 16; ++r)
                acc[nt][r] = fminf(fminf(acc[nt][r], d0[r]), d1[r]); // v_min3
        }
    }

    // ---- epilogue: fold 32 cols (xor within 32-lane half), store rows ----
    float* rp = part + (size_t)(dir * MSPLIT + ms) * TOTALQ + rowstart;
    #pragma unroll
    for (int nt = 0; nt < WNT; ++nt) {
        f32x16 v = acc[nt];
        #pragma unroll
        for (int m = 1; m < 32; m <<= 1) {
            #pragma unroll
            for (int r = 0; r < 16; ++r)
                v[r] = fminf(v[r], __shfl_xor(v[r], m, 64));
        }
        #pragma unroll
        for (int r = 0; r < 16; ++r) {
            int row = (r & 3) + 8 * (r >> 2) + 4 * g;   // C/D row map (m74/m101)
            if (c == r) rp[nt * 32 + row] = v[r];
        }
    }
}

__global__ __launch_bounds__(BLK) void chamfer_reduce_kernel(
        const float* __restrict__ part, float* __restrict__ out)
{
    int gl = blockIdx.x * BLK + threadIdx.x;   // 0..65535
    int dir = gl >> 15, i = gl & (TOTALQ - 1);

    const float* p = part + (size_t)dir * MSPLIT * TOTALQ + i;
    float m = p[0];
    #pragma unroll
    for (int s = 1; s < MSPLIT; ++s)
        m = fminf(m, p[(size_t)s * TOTALQ]);

    float acc = m * (1.0f / (float)TOTALQ);
    #pragma unroll
    for (int off = 32; off > 0; off >>= 1)
        acc += __shfl_down(acc, off, 64);
    __shared__ float wsum[BLK / 64];
    int lane = threadIdx.x & 63, wid = threadIdx.x >> 6;
    if (lane == 0) wsum[wid] = acc;
    __syncthreads();
    if (threadIdx.x == 0) {
        float s = 0.0f;
        #pragma unroll
        for (int wv = 0; wv < BLK / 64; ++wv) s += wsum[wv];
        atomicAdd(out, s);
    }
}

extern "C" void kernel_launch(void* const* d_in, const int* in_sizes, int n_in,
                              void* d_out, int out_size, void* d_ws, size_t ws_size,
                              hipStream_t stream) {
    const float* pred   = (const float*)d_in[0];
    const float* target = (const float*)d_in[1];
    float*       out    = (float*)d_out;
    float*       part   = (float*)d_ws;   // 2 dirs x 8 slices x 32768 = 2 MB

    dim3 grid(TOTALQ / BROWS, MSPLIT, 2);   // 64 x 8 x 2 = 1024 blocks
    hipLaunchKernelGGL(chamfer_mega_kernel, grid, dim3(BLK), 0, stream,
                       pred, target, part, out);

    hipLaunchKernelGGL(chamfer_reduce_kernel, dim3(2 * TOTALQ / BLK), dim3(BLK),
                       0, stream, (const float*)part, out);
}

// Round 12
// 77.627 us; speedup vs baseline: 1.3639x; 1.1536x over previous
//
#include <hip/hip_runtime.h>
#include <hip/hip_bf16.h>

// Chamfer distance, B=4, N=M=8192, D=3, fp32.
// R11: operand-role swap to kill the epilogue shuffle storm. R10's epilogue
// ran 320 __shfl_xor per wave (min over D cols = cross-lane). Now the
// "min-over" points are MFMA operand A (staged in LDS, same payload bits)
// and the OUTPUT queries are operand B (register-resident, same payload
// bits): D[n][m] = dist(target_n, query_m), output index = col = lane,
// min-over-targets = fold of the 16 acc regs IN-LANE (+1 shfl for the
// g-half). Main loop identical: 2 ds_read_b128 + 8 VGPR-dst MFMA + 64 min3.
// Payload (verified absmax 0.0 since R7), k0..15 query x target:
//   -2h.h | -2l.h | -2h.l | qn.1 | 1.tn | 0
//   query vec:  [ax,ay,az, cx,cy,cz, ax,ay,az, qn1,qn2,qn3, 1,1,1, 0]
//   target vec: [hx,hy,hz, hx,hy,hz, lx,ly,lz, 1,1,1, tn1,tn2,tn3, 0]

typedef __attribute__((ext_vector_type(8)))  short short8;
typedef __attribute__((ext_vector_type(16))) float f32x16;

#define BATCH 4
#define NPTS 8192
#define TOTALQ (BATCH * NPTS)   // 32768
#define BLK 256
#define WNT 4                   // 32-col B tiles per wave -> 128 queries/wave
#define BCOLS 512               // query cols per block (4 waves)
#define MSPLIT 8                // target slices per batch
#define MC (NPTS / MSPLIT)      // 1024 targets per block, single LDS stage
#define MT_PER (MC / 32)        // 32 target tiles

__device__ __forceinline__ unsigned short f2bf(float f) {  // RTN-even
    unsigned int u = __float_as_uint(f);
    u += 0x7FFFu + ((u >> 16) & 1u);
    return (unsigned short)(u >> 16);
}
__device__ __forceinline__ float bf2f(unsigned short h) {
    return __uint_as_float(((unsigned int)h) << 16);
}
__device__ __forceinline__ unsigned int pk2(unsigned short a, unsigned short b) {
    return (unsigned int)a | ((unsigned int)b << 16);
}

struct Payload {
    unsigned short hx, hy, hz, lx, ly, lz, n1, n2, n3;
};
__device__ __forceinline__ Payload split_point(float x, float y, float z) {
    Payload P;
    P.hx = f2bf(x);  P.hy = f2bf(y);  P.hz = f2bf(z);
    P.lx = f2bf(x - bf2f(P.hx));
    P.ly = f2bf(y - bf2f(P.hy));
    P.lz = f2bf(z - bf2f(P.hz));
    float nrm = fmaf(z, z, fmaf(y, y, x * x));
    P.n1 = f2bf(nrm);
    float r1 = nrm - bf2f(P.n1);
    P.n2 = f2bf(r1);
    P.n3 = f2bf(r1 - bf2f(P.n2));
    return P;
}

__global__ __launch_bounds__(BLK) void chamfer_mega_kernel(
        const float* __restrict__ pred, const float* __restrict__ target,
        float* __restrict__ part, float* __restrict__ out)
{
    const int dir = blockIdx.z;
    const float* __restrict__ Q  = dir ? target : pred;   // outputs (B cols)
    const float* __restrict__ Tg = dir ? pred : target;   // min-over (A rows, LDS)

    const int nch = blockIdx.x;            // 0..63 (512-query-col chunk)
    const int b   = nch >> 4;              // batch (16 chunks per batch)
    const int ms  = blockIdx.y;            // 0..7 target slice
    const int w    = threadIdx.x >> 6;
    const int lane = threadIdx.x & 63;
    const int c = lane & 31;               // row (A) / col (B) within tile
    const int g = lane >> 5;               // k-half
    const unsigned short ONE = 0x3F80;

    if (blockIdx.x == 0 && blockIdx.y == 0 && blockIdx.z == 0 &&
        threadIdx.x == 0) out[0] = 0.0f;   // consumed after kernel boundary

    __shared__ uint4 ldsb[2][MC];          // 32 KB (two k-halves)

    // ---- stage MC target points: raw read -> payload -> LDS (A operand) ----
    #pragma unroll
    for (int j = 0; j < MC / BLK; ++j) {
        int p = j * BLK + threadIdx.x;
        size_t gp = (size_t)b * NPTS + (size_t)ms * MC + p;
        float x = Tg[3 * gp], y = Tg[3 * gp + 1], z = Tg[3 * gp + 2];
        Payload P = split_point(x, y, z);
        ldsb[0][p] = (uint4){ pk2(P.hx, P.hy), pk2(P.hz, P.hx),
                              pk2(P.hy, P.hz), pk2(P.lx, P.ly) };
        ldsb[1][p] = (uint4){ pk2(P.lz, ONE), pk2(ONE, ONE),
                              pk2(P.n1, P.n2), pk2(P.n3, 0) };
    }

    // ---- B fragments (queries): in-register pack, col = colstart + nt*32 + c ----
    const int colstart = nch * BCOLS + w * (WNT * 32);
    short8 bq[WNT];
    #pragma unroll
    for (int nt = 0; nt < WNT; ++nt) {
        int r = colstart + nt * 32 + c;
        float x = Q[3 * r], y = Q[3 * r + 1], z = Q[3 * r + 2];
        Payload P = split_point(x, y, z);
        unsigned short ax = f2bf(-2.f * bf2f(P.hx)),
                       ay = f2bf(-2.f * bf2f(P.hy)),
                       az = f2bf(-2.f * bf2f(P.hz));
        unsigned short cx = f2bf(-2.f * bf2f(P.lx)),
                       cy = f2bf(-2.f * bf2f(P.ly)),
                       cz = f2bf(-2.f * bf2f(P.lz));
        uint4 h0 = { pk2(ax, ay), pk2(az, cx), pk2(cy, cz), pk2(ax, ay) };
        uint4 h1 = { pk2(az, P.n1), pk2(P.n2, P.n3), pk2(ONE, ONE), pk2(ONE, 0) };
        uint4 sel = g ? h1 : h0;
        bq[nt] = *(short8*)&sel;
    }

    f32x16 acc[WNT];
    #pragma unroll
    for (int nt = 0; nt < WNT; ++nt)
        #pragma unroll
        for (int r = 0; r < 16; ++r) acc[nt][r] = 3.4e38f;

    f32x16 vzero;
    #pragma unroll
    for (int r = 0; r < 16; ++r) vzero[r] = 0.0f;

    __syncthreads();

    const ushort* ldsu = (const ushort*)&ldsb[g][0];   // this lane's k-half

    // ---- main loop: 2 ds_read_b128 (A target tiles) + 8 MFMA + 64 min3 ----
    for (int mt = 0; mt < MT_PER; mt += 2) {
        short8 at0 = *(const short8*)(ldsu + (mt * 32 + c) * 8);
        short8 at1 = *(const short8*)(ldsu + ((mt + 1) * 32 + c) * 8);
        #pragma unroll
        for (int nt = 0; nt < WNT; ++nt) {
            f32x16 d0, d1;
            // A = target tile (LDS), B = query tile (regs); VGPR dst.
            // s_nop pads the MFMA-write -> VALU-read hazard (asm is opaque
            // to the hazard recognizer).
            asm("v_mfma_f32_32x32x16_bf16 %0, %2, %4, %5\n\t"
                "v_mfma_f32_32x32x16_bf16 %1, %3, %4, %5\n\t"
                "s_nop 7\n\t"
                "s_nop 7"
                : "=&v"(d0), "=&v"(d1)
                : "v"(at0), "v"(at1), "v"(bq[nt]), "v"(vzero));
            #pragma unroll
            for (int r = 0; r < 16; ++r)
                acc[nt][r] = fminf(fminf(acc[nt][r], d0[r]), d1[r]); // v_min3
        }
    }

    // ---- epilogue: min over the 16 regs (rows) in-lane + 1 shfl for g ----
    float* rp = part + (size_t)(dir * MSPLIT + ms) * TOTALQ;
    #pragma unroll
    for (int nt = 0; nt < WNT; ++nt) {
        f32x16 v = acc[nt];
        float m0 = fminf(fminf(v[0],  v[1]),  fminf(v[2],  v[3]));
        float m1 = fminf(fminf(v[4],  v[5]),  fminf(v[6],  v[7]));
        float m2 = fminf(fminf(v[8],  v[9]),  fminf(v[10], v[11]));
        float m3 = fminf(fminf(v[12], v[13]), fminf(v[14], v[15]));
        float m  = fminf(fminf(m0, m1), fminf(m2, m3));
        m = fminf(m, __shfl_xor(m, 32, 64));    // fold the two k-half rows
        if (g == 0) rp[colstart + nt * 32 + c] = m;
    }
}

__global__ __launch_bounds__(BLK) void chamfer_reduce_kernel(
        const float* __restrict__ part, float* __restrict__ out)
{
    int gl = blockIdx.x * BLK + threadIdx.x;   // 0..65535
    int dir = gl >> 15, i = gl & (TOTALQ - 1);

    const float* p = part + (size_t)dir * MSPLIT * TOTALQ + i;
    float m = p[0];
    #pragma unroll
    for (int s = 1; s < MSPLIT; ++s)
        m = fminf(m, p[(size_t)s * TOTALQ]);

    float acc = m * (1.0f / (float)TOTALQ);
    #pragma unroll
    for (int off = 32; off > 0; off >>= 1)
        acc += __shfl_down(acc, off, 64);
    __shared__ float wsum[BLK / 64];
    int lane = threadIdx.x & 63, wid = threadIdx.x >> 6;
    if (lane == 0) wsum[wid] = acc;
    __syncthreads();
    if (threadIdx.x == 0) {
        float s = 0.0f;
        #pragma unroll
        for (int wv = 0; wv < BLK / 64; ++wv) s += wsum[wv];
        atomicAdd(out, s);
    }
}

extern "C" void kernel_launch(void* const* d_in, const int* in_sizes, int n_in,
                              void* d_out, int out_size, void* d_ws, size_t ws_size,
                              hipStream_t stream) {
    const float* pred   = (const float*)d_in[0];
    const float* target = (const float*)d_in[1];
    float*       out    = (float*)d_out;
    float*       part   = (float*)d_ws;   // 2 dirs x 8 slices x 32768 = 2 MB

    dim3 grid(TOTALQ / BCOLS, MSPLIT, 2);   // 64 x 8 x 2 = 1024 blocks
    hipLaunchKernelGGL(chamfer_mega_kernel, grid, dim3(BLK), 0, stream,
                       pred, target, part, out);

    hipLaunchKernelGGL(chamfer_reduce_kernel, dim3(2 * TOTALQ / BLK), dim3(BLK),
                       0, stream, (const float*)part, out);
}